// Round 3
// baseline (184.899 us; speedup 1.0000x reference)
//
#include <hip/hip_runtime.h>

// DynamicMaskHead: fused CondInst mask-head MLP + aligned_bilinear x2 upsample.
// Grid: 1024 blocks = 256 instances x 4 quarters (64 out rows each).
// Block: 512 threads, __launch_bounds__(512,8) -> VGPR<=64, 32 waves/CU.
// LDS: 33 logit rows x 192 cols x 4B = 25,344 B -> 4 blocks/CU.
// 2 px/thread via float2 ext-vector -> v_pk_fma_f32, low register pressure.

#define HI 128
#define WI 192
#define HW_ (HI * WI)        // 24576
#define NP 169
#define NOUT_W 384
#define NOUT_H 256

typedef float v2f __attribute__((ext_vector_type(2)));

__device__ __forceinline__ v2f splat(float x) { v2f r; r.x = x; r.y = x; return r; }
__device__ __forceinline__ v2f vfma(v2f a, v2f b, v2f c) {
    return __builtin_elementwise_fma(a, b, c);
}
__device__ __forceinline__ v2f vrelu(v2f a) {
    return __builtin_elementwise_max(a, splat(0.0f));
}

__global__ __launch_bounds__(512, 8) void dynmask_kernel(
    const float* __restrict__ feats,    // [2,8,128,192]
    const float* __restrict__ params,   // [256,169]
    const float* __restrict__ locs,     // [256,2]
    const float* __restrict__ soi,      // [5]
    const int*   __restrict__ im_inds,  // [256]
    const int*   __restrict__ lvls,     // [256]
    float*       __restrict__ out)      // [256,1,256,384]
{
    __shared__ __align__(16) float L[33 * WI];   // logit rows R0..R0+32

    const int b  = blockIdx.x;
    const int n  = b >> 2;       // instance
    const int qq = b & 3;        // quarter: out rows qq*64 .. qq*64+63
    const int t  = threadIdx.x;
    const int R0 = (qq == 0) ? 0 : (32 * qq - 1);  // first logit row in LDS

    const int   im    = im_inds[n];
    const float s     = soi[lvls[n]];
    const float inv_s = 1.0f / s;
    const float ixv   = locs[2 * n + 0];
    const float iyv   = locs[2 * n + 1];
    const float* __restrict__ P = params + n * NP;   // block-uniform -> s_loads
    const float* __restrict__ F = feats + im * (8 * HW_);

    // rel_x(px) = (ixv - (px*8+4))/s = ax - px*step ; rel_y analogous
    const float step = 8.0f * inv_s;
    const float ax   = (ixv - 4.0f) * inv_s;
    const float ay   = (iyv - 4.0f) * inv_s;

    // ---------------- Phase 1: MLP -> logits in LDS ----------------
    // 33 rows * 192 cols = 6336 px = 3168 pairs (96 pairs per row).
    for (int idx = t; idx < 3168; idx += 512) {
        const int r   = idx / 96;
        const int c2  = idx - r * 96;
        const int py  = R0 + r;
        const int px0 = c2 * 2;
        const int gp  = py * WI + px0;          // global pixel (even)

        const float ry  = ay - (float)py * step;
        const float rx0 = ax - (float)px0 * step;
        v2f rx; rx.x = rx0; rx.y = rx0 - step;

        v2f fv[8];
        #pragma unroll
        for (int k = 0; k < 8; ++k)
            fv[k] = *reinterpret_cast<const v2f*>(F + k * HW_ + gp);

        // layer 0: 10 -> 8, relu.  w0[o][i]=P[o*10+i], b0[o]=P[152+o]
        v2f h0[8];
        #pragma unroll
        for (int o = 0; o < 8; ++o) {
            const float base = fmaf(P[o * 10 + 1], ry, P[152 + o]);
            h0[o] = vfma(splat(P[o * 10 + 0]), rx, splat(base));
            #pragma unroll
            for (int k = 0; k < 8; ++k)
                h0[o] = vfma(splat(P[o * 10 + 2 + k]), fv[k], h0[o]);
            h0[o] = vrelu(h0[o]);
        }

        // layer 1: 8 -> 8, relu.  w1[o][i]=P[80+o*8+i], b1[o]=P[160+o]
        v2f h1[8];
        #pragma unroll
        for (int o = 0; o < 8; ++o) {
            h1[o] = splat(P[160 + o]);
            #pragma unroll
            for (int i = 0; i < 8; ++i)
                h1[o] = vfma(splat(P[80 + o * 8 + i]), h0[i], h1[o]);
            h1[o] = vrelu(h1[o]);
        }

        // layer 2: 8 -> 1.  w2[i]=P[144+i], b2=P[168]
        v2f lg = splat(P[168]);
        #pragma unroll
        for (int i = 0; i < 8; ++i)
            lg = vfma(splat(P[144 + i]), h1[i], lg);

        *reinterpret_cast<v2f*>(&L[idx * 2]) = lg;
    }

    __syncthreads();

    // ---------------- Phase 2: aligned_bilinear x2 ----------------
    // out[y][x] = interp[max(y-1,0)][max(x-1,0)]
    //   rows: ry0=iy2>>1, fy=iy2&1 -> row ry0 or avg(ry0, min(ry0+1,127))
    //   cols: out[2m]=0.5*(v[m-1]+v[m]) (clamp m-1>=0), out[2m+1]=v[m]
    // Each thread: 8 output px from a float4 of v (+1 left neighbor).
    const int Y0 = qq << 6;
    float* __restrict__ O = out + n * (NOUT_H * NOUT_W) + Y0 * NOUT_W;
    for (int g = t; g < 3072; g += 512) {     // 64 rows * 48 groups, 6 iters
        const int yq = g / 48;
        const int c  = g - yq * 48;
        const int y  = Y0 + yq;
        const int iy2 = (y == 0) ? 0 : (y - 1);
        const int ry0 = iy2 >> 1;
        const int fy  = iy2 & 1;
        const int lr0 = ry0 - R0;
        const int j0  = c << 2;
        const int jm  = (c == 0) ? 0 : (j0 - 1);

        const float* row0 = &L[lr0 * WI];
        float4 v  = *reinterpret_cast<const float4*>(row0 + j0);
        float  vm = row0[jm];
        if (fy) {
            const int lr1 = min(ry0 + 1, HI - 1) - R0;
            const float* row1 = &L[lr1 * WI];
            const float4 w  = *reinterpret_cast<const float4*>(row1 + j0);
            const float  wm = row1[jm];
            v.x = 0.5f * (v.x + w.x); v.y = 0.5f * (v.y + w.y);
            v.z = 0.5f * (v.z + w.z); v.w = 0.5f * (v.w + w.w);
            vm  = 0.5f * (vm + wm);
        }
        float4 r0, r1;
        r0.x = 0.5f * (vm + v.x);  r0.y = v.x;
        r0.z = 0.5f * (v.x + v.y); r0.w = v.y;
        r1.x = 0.5f * (v.y + v.z); r1.y = v.z;
        r1.z = 0.5f * (v.z + v.w); r1.w = v.w;

        float* o8 = O + (g << 3);
        *reinterpret_cast<float4*>(o8)     = r0;
        *reinterpret_cast<float4*>(o8 + 4) = r1;
    }
}

extern "C" void kernel_launch(void* const* d_in, const int* in_sizes, int n_in,
                              void* d_out, int out_size, void* d_ws, size_t ws_size,
                              hipStream_t stream) {
    const float* feats   = (const float*)d_in[0];
    const float* params  = (const float*)d_in[1];
    const float* locs    = (const float*)d_in[2];
    const float* soi     = (const float*)d_in[3];
    const int*   im_inds = (const int*)d_in[4];
    const int*   lvls    = (const int*)d_in[5];
    float*       out     = (float*)d_out;
    dynmask_kernel<<<1024, 512, 0, stream>>>(feats, params, locs, soi, im_inds, lvls, out);
}

// Round 4
// 161.612 us; speedup vs baseline: 1.1441x; 1.1441x over previous
//
#include <hip/hip_runtime.h>

// DynamicMaskHead: fused CondInst mask-head MLP + aligned_bilinear x2 upsample.
// Grid: 1024 blocks = 256 instances x 4 quarters (64 out rows each) = 4 blocks/CU.
// Block: 512 threads. __launch_bounds__(512,4): allocator cap 128 VGPRs -> no
// spill (round-3's (512,8) gave a 32-VGPR budget and +45MB scratch traffic).
// Actual usage ~56 VGPRs -> HW can still co-schedule 8 waves/SIMD.
// LDS: 33 logit rows x 192 cols x 4B = 25,344 B -> 4 blocks/CU co-resident.
// 2 px/thread via float2 ext-vector -> v_pk_fma_f32.

#define HI 128
#define WI 192
#define HW_ (HI * WI)        // 24576
#define NP 169
#define NOUT_W 384
#define NOUT_H 256

typedef float v2f __attribute__((ext_vector_type(2)));

__device__ __forceinline__ v2f splat(float x) { v2f r; r.x = x; r.y = x; return r; }
__device__ __forceinline__ v2f vfma(v2f a, v2f b, v2f c) {
    return __builtin_elementwise_fma(a, b, c);
}
__device__ __forceinline__ v2f vrelu(v2f a) {
    return __builtin_elementwise_max(a, splat(0.0f));
}

__global__ __launch_bounds__(512, 4) void dynmask_kernel(
    const float* __restrict__ feats,    // [2,8,128,192]
    const float* __restrict__ params,   // [256,169]
    const float* __restrict__ locs,     // [256,2]
    const float* __restrict__ soi,      // [5]
    const int*   __restrict__ im_inds,  // [256]
    const int*   __restrict__ lvls,     // [256]
    float*       __restrict__ out)      // [256,1,256,384]
{
    __shared__ __align__(16) float L[33 * WI];   // logit rows R0..R0+32

    const int b  = blockIdx.x;
    const int n  = b >> 2;       // instance
    const int qq = b & 3;        // quarter: out rows qq*64 .. qq*64+63
    const int t  = threadIdx.x;
    const int R0 = (qq == 0) ? 0 : (32 * qq - 1);  // first logit row in LDS

    const int   im    = im_inds[n];
    const float s     = soi[lvls[n]];
    const float inv_s = 1.0f / s;
    const float ixv   = locs[2 * n + 0];
    const float iyv   = locs[2 * n + 1];
    const float* __restrict__ P = params + n * NP;   // block-uniform -> s_loads
    const float* __restrict__ F = feats + im * (8 * HW_);

    // rel_x(px) = (ixv - (px*8+4))/s = ax - px*step ; rel_y analogous
    const float step = 8.0f * inv_s;
    const float ax   = (ixv - 4.0f) * inv_s;
    const float ay   = (iyv - 4.0f) * inv_s;

    // ---------------- Phase 1: MLP -> logits in LDS ----------------
    // 33 rows * 192 cols = 6336 px = 3168 pairs (96 pairs per row).
    for (int idx = t; idx < 3168; idx += 512) {
        const int r   = idx / 96;
        const int c2  = idx - r * 96;
        const int py  = R0 + r;
        const int px0 = c2 * 2;
        const int gp  = py * WI + px0;          // global pixel (even)

        const float ry  = ay - (float)py * step;
        const float rx0 = ax - (float)px0 * step;
        v2f rx; rx.x = rx0; rx.y = rx0 - step;

        v2f fv[8];
        #pragma unroll
        for (int k = 0; k < 8; ++k)
            fv[k] = *reinterpret_cast<const v2f*>(F + k * HW_ + gp);

        // layer 0: 10 -> 8, relu.  w0[o][i]=P[o*10+i], b0[o]=P[152+o]
        v2f h0[8];
        #pragma unroll
        for (int o = 0; o < 8; ++o) {
            const float base = fmaf(P[o * 10 + 1], ry, P[152 + o]);
            h0[o] = vfma(splat(P[o * 10 + 0]), rx, splat(base));
            #pragma unroll
            for (int k = 0; k < 8; ++k)
                h0[o] = vfma(splat(P[o * 10 + 2 + k]), fv[k], h0[o]);
            h0[o] = vrelu(h0[o]);
        }

        // layer 1: 8 -> 8, relu.  w1[o][i]=P[80+o*8+i], b1[o]=P[160+o]
        v2f h1[8];
        #pragma unroll
        for (int o = 0; o < 8; ++o) {
            h1[o] = splat(P[160 + o]);
            #pragma unroll
            for (int i = 0; i < 8; ++i)
                h1[o] = vfma(splat(P[80 + o * 8 + i]), h0[i], h1[o]);
            h1[o] = vrelu(h1[o]);
        }

        // layer 2: 8 -> 1.  w2[i]=P[144+i], b2=P[168]
        v2f lg = splat(P[168]);
        #pragma unroll
        for (int i = 0; i < 8; ++i)
            lg = vfma(splat(P[144 + i]), h1[i], lg);

        *reinterpret_cast<v2f*>(&L[idx * 2]) = lg;
    }

    __syncthreads();

    // ---------------- Phase 2: aligned_bilinear x2 ----------------
    // out[y][x] = interp[max(y-1,0)][max(x-1,0)]
    //   rows: ry0=iy2>>1, fy=iy2&1 -> row ry0 or avg(ry0, min(ry0+1,127))
    //   cols: out[2m]=0.5*(v[m-1]+v[m]) (clamp m-1>=0), out[2m+1]=v[m]
    // Each thread: 8 output px from a float4 of v (+1 left neighbor).
    const int Y0 = qq << 6;
    float* __restrict__ O = out + n * (NOUT_H * NOUT_W) + Y0 * NOUT_W;
    for (int g = t; g < 3072; g += 512) {     // 64 rows * 48 groups, 6 iters
        const int yq = g / 48;
        const int c  = g - yq * 48;
        const int y  = Y0 + yq;
        const int iy2 = (y == 0) ? 0 : (y - 1);
        const int ry0 = iy2 >> 1;
        const int fy  = iy2 & 1;
        const int lr0 = ry0 - R0;
        const int j0  = c << 2;
        const int jm  = (c == 0) ? 0 : (j0 - 1);

        const float* row0 = &L[lr0 * WI];
        float4 v  = *reinterpret_cast<const float4*>(row0 + j0);
        float  vm = row0[jm];
        if (fy) {
            const int lr1 = min(ry0 + 1, HI - 1) - R0;
            const float* row1 = &L[lr1 * WI];
            const float4 w  = *reinterpret_cast<const float4*>(row1 + j0);
            const float  wm = row1[jm];
            v.x = 0.5f * (v.x + w.x); v.y = 0.5f * (v.y + w.y);
            v.z = 0.5f * (v.z + w.z); v.w = 0.5f * (v.w + w.w);
            vm  = 0.5f * (vm + wm);
        }
        float4 r0, r1;
        r0.x = 0.5f * (vm + v.x);  r0.y = v.x;
        r0.z = 0.5f * (v.x + v.y); r0.w = v.y;
        r1.x = 0.5f * (v.y + v.z); r1.y = v.z;
        r1.z = 0.5f * (v.z + v.w); r1.w = v.w;

        float* o8 = O + (g << 3);
        *reinterpret_cast<float4*>(o8)     = r0;
        *reinterpret_cast<float4*>(o8 + 4) = r1;
    }
}

extern "C" void kernel_launch(void* const* d_in, const int* in_sizes, int n_in,
                              void* d_out, int out_size, void* d_ws, size_t ws_size,
                              hipStream_t stream) {
    const float* feats   = (const float*)d_in[0];
    const float* params  = (const float*)d_in[1];
    const float* locs    = (const float*)d_in[2];
    const float* soi     = (const float*)d_in[3];
    const int*   im_inds = (const int*)d_in[4];
    const int*   lvls    = (const int*)d_in[5];
    float*       out     = (float*)d_out;
    dynmask_kernel<<<1024, 512, 0, stream>>>(feats, params, locs, soi, im_inds, lvls, out);
}

// Round 5
// 154.326 us; speedup vs baseline: 1.1981x; 1.0472x over previous
//
#include <hip/hip_runtime.h>

// DynamicMaskHead, two-kernel split:
//   A) mlp_kernel:      per-instance 10->8->8->1 MLP, logits (fp32) -> d_ws
//   B) upsample_kernel: aligned_bilinear x2 from d_ws -> out
// Rationale (r5): fused variants pinned at ~70us across 3 different bodies;
// split decomposes the cost in rocprof and removes halo + barrier coupling.
// MLP uses scalar fmaf with block-uniform weights (v_fmac with SGPR operand).

#define HI 128
#define WI 192
#define HW_ (HI * WI)        // 24576
#define NP 169
#define NOUT_W 384
#define NOUT_H 256
#define LOGITS_BYTES (256u * (unsigned)HW_ * 4u)   // 25,165,824

// ---------------- Kernel A: MLP -> logits[256][128*192] ----------------
// 6144 blocks = 256 instances x 24 chunks; 256 thr; 4 px/thread (one row).
__global__ __launch_bounds__(256, 4) void mlp_kernel(
    const float* __restrict__ feats,    // [2,8,128,192]
    const float* __restrict__ params,   // [256,169]
    const float* __restrict__ locs,     // [256,2]
    const float* __restrict__ soi,      // [5]
    const int*   __restrict__ im_inds,  // [256]
    const int*   __restrict__ lvls,     // [256]
    float*       __restrict__ logits)   // [256,128*192]
{
    const int b     = blockIdx.x;
    const int n     = b / 24;            // instance (block-uniform)
    const int chunk = b - n * 24;
    const int t     = threadIdx.x;
    const int p     = chunk * 1024 + (t << 2);   // 4 consecutive px, same row

    const int   im    = im_inds[n];
    const float s     = soi[lvls[n]];
    const float inv_s = 1.0f / s;
    const float* __restrict__ P = params + n * NP;   // uniform -> s_loads
    const float* __restrict__ F = feats + im * (8 * HW_);

    const float step = 8.0f * inv_s;
    const float ax   = (locs[2 * n + 0] - 4.0f) * inv_s;
    const float ay   = (locs[2 * n + 1] - 4.0f) * inv_s;

    const int py  = p / WI;              // 192%4==0 -> all 4 px share the row
    const int px0 = p - py * WI;
    const float ry  = ay - (float)py * step;
    const float rx0 = ax - (float)px0 * step;
    const float rx[4] = {rx0, rx0 - step, rx0 - 2.0f * step, rx0 - 3.0f * step};

    float fv[8][4];
    #pragma unroll
    for (int k = 0; k < 8; ++k) {
        const float4 v = *reinterpret_cast<const float4*>(F + k * HW_ + p);
        fv[k][0] = v.x; fv[k][1] = v.y; fv[k][2] = v.z; fv[k][3] = v.w;
    }

    // layer 0: 10 -> 8, relu.  w0[o][i]=P[o*10+i], b0[o]=P[152+o]
    float h0[8][4];
    #pragma unroll
    for (int o = 0; o < 8; ++o) {
        const float base = fmaf(P[o * 10 + 1], ry, P[152 + o]);
        const float wx   = P[o * 10 + 0];
        #pragma unroll
        for (int j = 0; j < 4; ++j) h0[o][j] = fmaf(wx, rx[j], base);
        #pragma unroll
        for (int k = 0; k < 8; ++k) {
            const float w = P[o * 10 + 2 + k];
            #pragma unroll
            for (int j = 0; j < 4; ++j) h0[o][j] = fmaf(w, fv[k][j], h0[o][j]);
        }
        #pragma unroll
        for (int j = 0; j < 4; ++j) h0[o][j] = fmaxf(h0[o][j], 0.0f);
    }

    // layer 1: 8 -> 8, relu.  w1[o][i]=P[80+o*8+i], b1[o]=P[160+o]
    float h1[8][4];
    #pragma unroll
    for (int o = 0; o < 8; ++o) {
        const float bb = P[160 + o];
        #pragma unroll
        for (int j = 0; j < 4; ++j) h1[o][j] = bb;
        #pragma unroll
        for (int i = 0; i < 8; ++i) {
            const float w = P[80 + o * 8 + i];
            #pragma unroll
            for (int j = 0; j < 4; ++j) h1[o][j] = fmaf(w, h0[i][j], h1[o][j]);
        }
        #pragma unroll
        for (int j = 0; j < 4; ++j) h1[o][j] = fmaxf(h1[o][j], 0.0f);
    }

    // layer 2: 8 -> 1.  w2[i]=P[144+i], b2=P[168]
    float lg[4];
    const float b2 = P[168];
    #pragma unroll
    for (int j = 0; j < 4; ++j) lg[j] = b2;
    #pragma unroll
    for (int i = 0; i < 8; ++i) {
        const float w = P[144 + i];
        #pragma unroll
        for (int j = 0; j < 4; ++j) lg[j] = fmaf(w, h1[i][j], lg[j]);
    }

    float4 st; st.x = lg[0]; st.y = lg[1]; st.z = lg[2]; st.w = lg[3];
    *reinterpret_cast<float4*>(logits + n * HW_ + p) = st;
}

// ---------------- Kernel B: aligned_bilinear x2 from logits ----------------
// out[y][x] = interp[max(y-1,0)][max(x-1,0)]
//   rows: ry0=iy2>>1, fy=iy2&1 -> row ry0 or avg(ry0, min(ry0+1,127))
//   cols: out[2m]=0.5*(v[m-1]+v[m]) (clamp m-1>=0), out[2m+1]=v[m]
// 1024 blocks = 256 instances x 4 quarters (64 out rows); 256 thr; 8 px/thr.
// Per-block logit working set: 33 rows * 768B = ~25KB -> L1-resident.
__global__ __launch_bounds__(256, 4) void upsample_kernel(
    const float* __restrict__ logits,   // [256,128*192]
    float*       __restrict__ out)      // [256,1,256,384]
{
    const int b  = blockIdx.x;
    const int n  = b >> 2;
    const int qq = b & 3;
    const int t  = threadIdx.x;
    const int Y0 = qq << 6;

    const float* __restrict__ Lg = logits + n * HW_;
    float* __restrict__ O = out + n * (NOUT_H * NOUT_W) + Y0 * NOUT_W;

    for (int g = t; g < 3072; g += 256) {     // 64 rows * 48 groups
        const int yq = g / 48;
        const int c  = g - yq * 48;
        const int y  = Y0 + yq;
        const int iy2 = (y == 0) ? 0 : (y - 1);
        const int ry0 = iy2 >> 1;
        const int fy  = iy2 & 1;
        const int j0  = c << 2;
        const int jm  = (c == 0) ? 0 : (j0 - 1);

        const float* row0 = Lg + ry0 * WI;
        float4 v  = *reinterpret_cast<const float4*>(row0 + j0);
        float  vm = row0[jm];
        if (fy) {
            const float* row1 = Lg + min(ry0 + 1, HI - 1) * WI;
            const float4 w  = *reinterpret_cast<const float4*>(row1 + j0);
            const float  wm = row1[jm];
            v.x = 0.5f * (v.x + w.x); v.y = 0.5f * (v.y + w.y);
            v.z = 0.5f * (v.z + w.z); v.w = 0.5f * (v.w + w.w);
            vm  = 0.5f * (vm + wm);
        }
        float4 r0, r1;
        r0.x = 0.5f * (vm + v.x);  r0.y = v.x;
        r0.z = 0.5f * (v.x + v.y); r0.w = v.y;
        r1.x = 0.5f * (v.y + v.z); r1.y = v.z;
        r1.z = 0.5f * (v.z + v.w); r1.w = v.w;

        float* o8 = O + (g << 3);
        *reinterpret_cast<float4*>(o8)     = r0;
        *reinterpret_cast<float4*>(o8 + 4) = r1;
    }
}

// ---------------- Fallback: fused single kernel (round-4 version) ----------
__global__ __launch_bounds__(512, 4) void dynmask_fused(
    const float* __restrict__ feats, const float* __restrict__ params,
    const float* __restrict__ locs, const float* __restrict__ soi,
    const int* __restrict__ im_inds, const int* __restrict__ lvls,
    float* __restrict__ out)
{
    __shared__ __align__(16) float L[33 * WI];
    const int b  = blockIdx.x;
    const int n  = b >> 2;
    const int qq = b & 3;
    const int t  = threadIdx.x;
    const int R0 = (qq == 0) ? 0 : (32 * qq - 1);

    const int   im    = im_inds[n];
    const float s     = soi[lvls[n]];
    const float inv_s = 1.0f / s;
    const float* __restrict__ P = params + n * NP;
    const float* __restrict__ F = feats + im * (8 * HW_);
    const float step = 8.0f * inv_s;
    const float ax   = (locs[2 * n + 0] - 4.0f) * inv_s;
    const float ay   = (locs[2 * n + 1] - 4.0f) * inv_s;

    for (int idx = t; idx < 3168; idx += 512) {
        const int r   = idx / 96;
        const int c2  = idx - r * 96;
        const int py  = R0 + r;
        const int px0 = c2 * 2;
        const int gp  = py * WI + px0;
        const float ry  = ay - (float)py * step;
        const float rx0 = ax - (float)px0 * step;
        const float rx[2] = {rx0, rx0 - step};

        float fv[8][2];
        #pragma unroll
        for (int k = 0; k < 8; ++k) {
            const float2 v = *reinterpret_cast<const float2*>(F + k * HW_ + gp);
            fv[k][0] = v.x; fv[k][1] = v.y;
        }
        float h0[8][2];
        #pragma unroll
        for (int o = 0; o < 8; ++o) {
            const float base = fmaf(P[o * 10 + 1], ry, P[152 + o]);
            #pragma unroll
            for (int j = 0; j < 2; ++j) h0[o][j] = fmaf(P[o * 10 + 0], rx[j], base);
            #pragma unroll
            for (int k = 0; k < 8; ++k)
                #pragma unroll
                for (int j = 0; j < 2; ++j) h0[o][j] = fmaf(P[o * 10 + 2 + k], fv[k][j], h0[o][j]);
            #pragma unroll
            for (int j = 0; j < 2; ++j) h0[o][j] = fmaxf(h0[o][j], 0.0f);
        }
        float h1[8][2];
        #pragma unroll
        for (int o = 0; o < 8; ++o) {
            #pragma unroll
            for (int j = 0; j < 2; ++j) h1[o][j] = P[160 + o];
            #pragma unroll
            for (int i = 0; i < 8; ++i)
                #pragma unroll
                for (int j = 0; j < 2; ++j) h1[o][j] = fmaf(P[80 + o * 8 + i], h0[i][j], h1[o][j]);
            #pragma unroll
            for (int j = 0; j < 2; ++j) h1[o][j] = fmaxf(h1[o][j], 0.0f);
        }
        float lg[2] = {P[168], P[168]};
        #pragma unroll
        for (int i = 0; i < 8; ++i)
            #pragma unroll
            for (int j = 0; j < 2; ++j) lg[j] = fmaf(P[144 + i], h1[i][j], lg[j]);
        L[idx * 2] = lg[0]; L[idx * 2 + 1] = lg[1];
    }
    __syncthreads();

    const int Y0 = qq << 6;
    float* __restrict__ O = out + n * (NOUT_H * NOUT_W) + Y0 * NOUT_W;
    for (int g = t; g < 3072; g += 512) {
        const int yq = g / 48;
        const int c  = g - yq * 48;
        const int y  = Y0 + yq;
        const int iy2 = (y == 0) ? 0 : (y - 1);
        const int ry0 = iy2 >> 1;
        const int fy  = iy2 & 1;
        const int lr0 = ry0 - R0;
        const int j0  = c << 2;
        const int jm  = (c == 0) ? 0 : (j0 - 1);
        const float* row0 = &L[lr0 * WI];
        float4 v  = *reinterpret_cast<const float4*>(row0 + j0);
        float  vm = row0[jm];
        if (fy) {
            const float* row1 = &L[(min(ry0 + 1, HI - 1) - R0) * WI];
            const float4 w  = *reinterpret_cast<const float4*>(row1 + j0);
            const float  wm = row1[jm];
            v.x = 0.5f * (v.x + w.x); v.y = 0.5f * (v.y + w.y);
            v.z = 0.5f * (v.z + w.z); v.w = 0.5f * (v.w + w.w);
            vm  = 0.5f * (vm + wm);
        }
        float4 r0, r1;
        r0.x = 0.5f * (vm + v.x);  r0.y = v.x;
        r0.z = 0.5f * (v.x + v.y); r0.w = v.y;
        r1.x = 0.5f * (v.y + v.z); r1.y = v.z;
        r1.z = 0.5f * (v.z + v.w); r1.w = v.w;
        float* o8 = O + (g << 3);
        *reinterpret_cast<float4*>(o8)     = r0;
        *reinterpret_cast<float4*>(o8 + 4) = r1;
    }
}

extern "C" void kernel_launch(void* const* d_in, const int* in_sizes, int n_in,
                              void* d_out, int out_size, void* d_ws, size_t ws_size,
                              hipStream_t stream) {
    const float* feats   = (const float*)d_in[0];
    const float* params  = (const float*)d_in[1];
    const float* locs    = (const float*)d_in[2];
    const float* soi     = (const float*)d_in[3];
    const int*   im_inds = (const int*)d_in[4];
    const int*   lvls    = (const int*)d_in[5];
    float*       out     = (float*)d_out;

    if (ws_size >= (size_t)LOGITS_BYTES) {
        float* logits = (float*)d_ws;
        mlp_kernel<<<6144, 256, 0, stream>>>(feats, params, locs, soi, im_inds, lvls, logits);
        upsample_kernel<<<1024, 256, 0, stream>>>(logits, out);
    } else {
        dynmask_fused<<<1024, 512, 0, stream>>>(feats, params, locs, soi, im_inds, lvls, out);
    }
}